// Round 7
// baseline (349.717 us; speedup 1.0000x reference)
//
#include <hip/hip_runtime.h>

// B=2, L=4096, D=512, H=8, DK=64. out = Attn(x W_qkv^T) W_o^T, fp32 io.
// R7: R4's proven attn structure (occupancy-scaled loop) with P region cut to
// swizzled stride-64 -> LDS exactly 32 KB (tests 128KB-usable-LDS hypothesis:
// 3 -> 4 blocks/CU). combine kernel fused into out_gemm A-staging.

#define Bq 2
#define Lq 4096
#define Dq 512
#define Hq 8
#define DKq 64

using short8  = __attribute__((ext_vector_type(8))) short;
using ushort8 = __attribute__((ext_vector_type(8))) unsigned short;
using float4v = __attribute__((ext_vector_type(4))) float;
typedef unsigned short u16;
typedef unsigned int   u32;

__device__ __forceinline__ u16 f2bf(float f) {
    u32 u = __float_as_uint(f);
    u += 0x7fffu + ((u >> 16) & 1u);   // RNE
    return (u16)(u >> 16);
}

__device__ __forceinline__ float4v mfma16(short8 a, short8 b, float4v c) {
    return __builtin_amdgcn_mfma_f32_16x16x32_bf16(a, b, c, 0, 0, 0);
}

__device__ __forceinline__ void gload_lds16(const u16* g, u16* l) {
    __builtin_amdgcn_global_load_lds(
        (const __attribute__((address_space(1))) unsigned int*)g,
        (__attribute__((address_space(3))) unsigned int*)l,
        16, 0, 0);
}

// ---------------- fused cast fp32 -> bf16 ----------------
__global__ __launch_bounds__(256) void castall(const float* __restrict__ x,
                                               const float* __restrict__ wq,
                                               const float* __restrict__ wo,
                                               u16* __restrict__ xb,
                                               u16* __restrict__ wqb,
                                               u16* __restrict__ wob) {
    int g = blockIdx.x;
    const float* s; u16* d; int base;
    if (g < 4096)      { s = x;  d = xb;  base = g * 1024; }
    else if (g < 4864) { s = wq; d = wqb; base = (g - 4096) * 1024; }
    else               { s = wo; d = wob; base = (g - 4864) * 1024; }
    int i = base + threadIdx.x * 4;
    float4 f = *(const float4*)&s[i];
    ushort4 o;
    o.x = f2bf(f.x); o.y = f2bf(f.y); o.z = f2bf(f.z); o.w = f2bf(f.w);
    *(ushort4*)&d[i] = o;
}

// ---------------- QKV proj: 128x128 tile; LDS-bounced coalesced epilogue -----
__global__ __launch_bounds__(256) void qkv_gemm(const u16* __restrict__ A,
                                                const u16* __restrict__ Bw,
                                                u16* __restrict__ qb,
                                                u16* __restrict__ kb,
                                                u16* __restrict__ vt) {
    __shared__ __align__(16) union {
        struct { u16 A[128 * 64]; u16 B[128 * 64]; } s;
        u16 epi[128 * 134];
    } sm;
    const int m0 = blockIdx.x * 128, n0 = blockIdx.y * 128;
    const int tid = threadIdx.x, w = tid >> 6, lane = tid & 63;
    const int l15 = lane & 15, quad = lane >> 4;
    const int wy = w & 1, wx = w >> 1;
    const int r8 = lane >> 3, c8 = lane & 7, csw = c8 ^ r8;
    const int sw = l15 & 7;

    float4v acc[4][4];
    float4v zero = {0.f, 0.f, 0.f, 0.f};
#pragma unroll
    for (int mi = 0; mi < 4; mi++)
#pragma unroll
        for (int ni = 0; ni < 4; ni++) acc[mi][ni] = zero;

    for (int k0 = 0; k0 < 512; k0 += 64) {
#pragma unroll
        for (int i = 0; i < 4; i++) {
            int row = w * 32 + i * 8;
            gload_lds16(&A[(size_t)(m0 + row + r8) * 512 + k0 + csw * 8], &sm.s.A[row * 64]);
            gload_lds16(&Bw[(size_t)(n0 + row + r8) * 512 + k0 + csw * 8], &sm.s.B[row * 64]);
        }
        __syncthreads();
        short8 af0[4], af1[4], bf0[4], bf1[4];
#pragma unroll
        for (int t = 0; t < 4; t++) {
            int rowA = wy * 64 + t * 16 + l15;
            af0[t] = *(const short8*)&sm.s.A[rowA * 64 + ((quad ^ sw) * 8)];
            af1[t] = *(const short8*)&sm.s.A[rowA * 64 + (((quad + 4) ^ sw) * 8)];
            int rowB = wx * 64 + t * 16 + l15;
            bf0[t] = *(const short8*)&sm.s.B[rowB * 64 + ((quad ^ sw) * 8)];
            bf1[t] = *(const short8*)&sm.s.B[rowB * 64 + (((quad + 4) ^ sw) * 8)];
        }
#pragma unroll
        for (int mi = 0; mi < 4; mi++)
#pragma unroll
            for (int ni = 0; ni < 4; ni++) {
                acc[mi][ni] = mfma16(af0[mi], bf0[ni], acc[mi][ni]);
                acc[mi][ni] = mfma16(af1[mi], bf1[ni], acc[mi][ni]);
            }
        __syncthreads();
    }

    const int sel = n0 >> 9;   // block-uniform: 0=q,1=k,2=v
    if (sel < 2) {
        const float sc = (sel == 0) ? 0.125f : 1.0f;
#pragma unroll
        for (int mi = 0; mi < 4; mi++)
#pragma unroll
            for (int ni = 0; ni < 4; ni++)
#pragma unroll
                for (int r = 0; r < 4; r++)
                    sm.epi[(wy * 64 + mi * 16 + quad * 4 + r) * 134 + wx * 64 + ni * 16 + l15] =
                        f2bf(acc[mi][ni][r] * sc);
        __syncthreads();
        u16* tgt = (sel == 0) ? qb : kb;
#pragma unroll
        for (int i = 0; i < 8; i++) {
            int flat = i * 2048 + tid * 8;
            int row = flat >> 7, col = flat & 127;
            ushort8 vv = *(const ushort8*)&sm.epi[row * 134 + col];
            int dg = (n0 & 511) + col, h = dg >> 6, dk = dg & 63;
            int mm = m0 + row, b = mm >> 12, l = mm & 4095;
            *(ushort8*)&tgt[((size_t)(b * Hq + h) * Lq + l) * DKq + dk] = vv;
        }
    } else {
#pragma unroll
        for (int mi = 0; mi < 4; mi++)
#pragma unroll
            for (int ni = 0; ni < 4; ni++) {
                ushort4 v4;
                v4.x = f2bf(acc[mi][ni][0]); v4.y = f2bf(acc[mi][ni][1]);
                v4.z = f2bf(acc[mi][ni][2]); v4.w = f2bf(acc[mi][ni][3]);
                *(ushort4*)&sm.epi[(wx * 64 + ni * 16 + l15) * 134 + wy * 64 + mi * 16 + quad * 4] = v4;
            }
        __syncthreads();
#pragma unroll
        for (int i = 0; i < 8; i++) {
            int flat = i * 2048 + tid * 8;
            int vrow = flat >> 7, vcol = flat & 127;
            ushort8 vv = *(const ushort8*)&sm.epi[vrow * 134 + vcol];
            int dg = (n0 & 511) + vrow, h = dg >> 6, dk = dg & 63;
            int mm = m0 + vcol, b = mm >> 12, l = mm & 4095;
            *(ushort8*)&vt[((size_t)(b * Hq + h) * DKq + dk) * Lq + l] = vv;
        }
    }
}

// ---------------- attention: R4 structure, P in swizzled stride-64 LDS -------
__global__ __launch_bounds__(256, 4) void attn_kern(const u16* __restrict__ qb,
                                                    const u16* __restrict__ kb,
                                                    const u16* __restrict__ vt,
                                                    _Float16* __restrict__ op0,
                                                    _Float16* __restrict__ op1,
                                                    float* __restrict__ denp) {
    __shared__ __align__(16) u16 Ks[64 * 64];   // 8 KB
    __shared__ __align__(16) u16 Vs[64 * 64];   // 8 KB
    __shared__ __align__(16) u16 Ps[4 * 32 * 64]; // 16 KB -> total exactly 32 KB
    const int g = blockIdx.x;          // 1024
    const int bh = (g & 7) * 2 + ((g >> 3) & 1);  // XCD-swizzled head
    const int rest = g >> 4;
    const int split = rest & 1;
    const int q0 = (rest >> 1) * 128;
    const int tid = threadIdx.x;
    const int w = tid >> 6, lane = tid & 63, l15 = lane & 15, quad = lane >> 4;
    const int r8 = lane >> 3, c8 = lane & 7, csw = c8 ^ r8;
    const int sw = l15 & 7;

    const u16* qbase = qb + (size_t)bh * Lq * DKq;
    const u16* kbase = kb + (size_t)bh * Lq * DKq;
    const u16* vbase = vt + (size_t)bh * DKq * Lq;

    short8 aq0[2], aq1[2];
#pragma unroll
    for (int s = 0; s < 2; s++) {
        int qrow = q0 + w * 32 + s * 16 + l15;
        aq0[s] = *(const short8*)&qbase[(size_t)qrow * DKq + quad * 8];
        aq1[s] = *(const short8*)&qbase[(size_t)qrow * DKq + 32 + quad * 8];
    }

    short8 ones8;
#pragma unroll
    for (int j = 0; j < 8; j++) ones8[j] = (short)0x3F80;  // bf16 1.0

    float4v zero = {0.f, 0.f, 0.f, 0.f};
    float4v oacc[2][4], den[2];
#pragma unroll
    for (int s = 0; s < 2; s++) {
        den[s] = zero;
#pragma unroll
        for (int n = 0; n < 4; n++) oacc[s][n] = zero;
    }

    u16* Pw = Ps + w * 32 * 64;
    const int j0base = split * 2048;

    for (int jt = 0; jt < 32; jt++) {
        int j0 = j0base + jt * 64;
        if (w < 2) {
#pragma unroll
            for (int i = 0; i < 4; i++) {
                int base = w * 32 + i * 8;
                gload_lds16(&kbase[(size_t)(j0 + base + r8) * DKq + csw * 8], &Ks[base * 64]);
            }
        } else {
#pragma unroll
            for (int i = 0; i < 4; i++) {
                int base = (w - 2) * 32 + i * 8;
                gload_lds16(&vbase[(size_t)(base + r8) * Lq + j0 + csw * 8], &Vs[base * 64]);
            }
        }
        __syncthreads();

        short8 kf0[4], kf1[4], vf0[4], vf1[4];
#pragma unroll
        for (int n = 0; n < 4; n++) {
            int row = n * 16 + l15;
            kf0[n] = *(const short8*)&Ks[row * 64 + ((quad ^ sw) * 8)];
            kf1[n] = *(const short8*)&Ks[row * 64 + (((quad + 4) ^ sw) * 8)];
            vf0[n] = *(const short8*)&Vs[row * 64 + ((quad ^ sw) * 8)];
            vf1[n] = *(const short8*)&Vs[row * 64 + (((quad + 4) ^ sw) * 8)];
        }

        // S^T = K Q^T -> P = exp -> LDS b64, swizzled stride-64 layout
#pragma unroll
        for (int s = 0; s < 2; s++) {
#pragma unroll
            for (int nk = 0; nk < 4; nk++) {
                float4v sv = zero;
                sv = mfma16(kf0[nk], aq0[s], sv);
                sv = mfma16(kf1[nk], aq1[s], sv);
                u32 u0 = __float_as_uint(__expf(sv[0])) + 0x8000u;
                u32 u1 = __float_as_uint(__expf(sv[1])) + 0x8000u;
                u32 u2 = __float_as_uint(__expf(sv[2])) + 0x8000u;
                u32 u3 = __float_as_uint(__expf(sv[3])) + 0x8000u;
                uint2 pv;
                pv.x = __builtin_amdgcn_perm(u1, u0, 0x07060302u);
                pv.y = __builtin_amdgcn_perm(u3, u2, 0x07060302u);
                int chunk = (nk * 2 + (quad >> 1)) ^ sw;     // = (key/8) ^ sw
                *(uint2*)&Pw[(s * 16 + l15) * 64 + chunk * 8 + (quad & 1) * 4] = pv;
            }
        }

        // O += P V ; den += P . 1
#pragma unroll
        for (int s = 0; s < 2; s++) {
            short8 ap0 = *(const short8*)&Pw[(s * 16 + l15) * 64 + ((quad ^ sw) * 8)];
            short8 ap1 = *(const short8*)&Pw[(s * 16 + l15) * 64 + (((quad + 4) ^ sw) * 8)];
            den[s] = mfma16(ap0, ones8, den[s]);
            den[s] = mfma16(ap1, ones8, den[s]);
#pragma unroll
            for (int n = 0; n < 4; n++) {
                oacc[s][n] = mfma16(ap0, vf0[n], oacc[s][n]);
                oacc[s][n] = mfma16(ap1, vf1[n], oacc[s][n]);
            }
        }
        __syncthreads();
    }

    // epilogue: write normalized partial O (fp16) + partial den (fp32)
    _Float16* op = split ? op1 : op0;
#pragma unroll
    for (int s = 0; s < 2; s++)
#pragma unroll
        for (int r = 0; r < 4; r++) {
            float dv = den[s][r];
            float rd = __builtin_amdgcn_rcpf(dv);
            int row = q0 + w * 32 + s * 16 + quad * 4 + r;
            if (l15 == 0) denp[(size_t)(split * 16 + bh) * Lq + row] = dv;
#pragma unroll
            for (int n = 0; n < 4; n++)
                op[((size_t)bh * Lq + row) * DKq + n * 16 + l15] =
                    (_Float16)(oacc[s][n][r] * rd);
        }
}

// ---------------- output projection with fused split-K combine --------------
// out[8192,512] = combine(op0,op1,denp) @ Wo^T ; head h == k-iter (DK=64)
__global__ __launch_bounds__(256) void out_gemm(const _Float16* __restrict__ op0,
                                                const _Float16* __restrict__ op1,
                                                const float* __restrict__ denp,
                                                const u16* __restrict__ Bw,
                                                float* __restrict__ out) {
    __shared__ __align__(16) union {
        struct { u16 A[128 * 64]; u16 B[128 * 64]; } s;
        float fepi[64 * 132];
    } sm;
    const int m0 = blockIdx.x * 128, n0 = blockIdx.y * 128;
    const int tid = threadIdx.x, w = tid >> 6, lane = tid & 63;
    const int l15 = lane & 15, quad = lane >> 4;
    const int wy = w & 1, wx = w >> 1;
    const int r8 = lane >> 3, c8 = lane & 7, csw = c8 ^ r8;
    const int sw = l15 & 7;

    float4v acc[4][4];
    float4v zero = {0.f, 0.f, 0.f, 0.f};
#pragma unroll
    for (int mi = 0; mi < 4; mi++)
#pragma unroll
        for (int ni = 0; ni < 4; ni++) acc[mi][ni] = zero;

    for (int k0 = 0; k0 < 512; k0 += 64) {
        const int kk = k0 >> 6;   // head index
#pragma unroll
        for (int i = 0; i < 4; i++) {
            int row = w * 32 + i * 8;
            // B: async DMA (bf16 Wo)
            gload_lds16(&Bw[(size_t)(n0 + row + r8) * 512 + k0 + csw * 8], &sm.s.B[row * 64]);
            // A: manual combined staging from op0/op1/denp
            int mm = m0 + row + r8;
            int b = mm >> 12, l = mm & 4095;
            int bh = b * Hq + kk;
            size_t rowoff = ((size_t)bh * Lq + l) * DKq + csw * 8;
            union { float4 f; _Float16 h[8]; } ua, ub;
            ua.f = *(const float4*)&op0[rowoff];
            ub.f = *(const float4*)&op1[rowoff];
            float d0 = denp[(size_t)bh * Lq + l];
            float d1 = denp[(size_t)(16 + bh) * Lq + l];
            float rs = __builtin_amdgcn_rcpf(d0 + d1);
            ushort8 ov;
#pragma unroll
            for (int j = 0; j < 8; j++)
                ov[j] = f2bf(((float)ua.h[j] * d0 + (float)ub.h[j] * d1) * rs);
            *(ushort8*)&sm.s.A[(row + r8) * 64 + c8 * 8] = ov;
        }
        __syncthreads();
        short8 af0[4], af1[4], bf0[4], bf1[4];
#pragma unroll
        for (int t = 0; t < 4; t++) {
            int rowA = wy * 64 + t * 16 + l15;
            af0[t] = *(const short8*)&sm.s.A[rowA * 64 + ((quad ^ sw) * 8)];
            af1[t] = *(const short8*)&sm.s.A[rowA * 64 + (((quad + 4) ^ sw) * 8)];
            int rowB = wx * 64 + t * 16 + l15;
            bf0[t] = *(const short8*)&sm.s.B[rowB * 64 + ((quad ^ sw) * 8)];
            bf1[t] = *(const short8*)&sm.s.B[rowB * 64 + (((quad + 4) ^ sw) * 8)];
        }
#pragma unroll
        for (int mi = 0; mi < 4; mi++)
#pragma unroll
            for (int ni = 0; ni < 4; ni++) {
                acc[mi][ni] = mfma16(af0[mi], bf0[ni], acc[mi][ni]);
                acc[mi][ni] = mfma16(af1[mi], bf1[ni], acc[mi][ni]);
            }
        __syncthreads();
    }

#pragma unroll
    for (int ph = 0; ph < 2; ph++) {
#pragma unroll
        for (int mh = 0; mh < 2; mh++) {
            int mi = ph * 2 + mh;
            int lr = wy * 32 + mh * 16 + quad * 4;
#pragma unroll
            for (int ni = 0; ni < 4; ni++)
#pragma unroll
                for (int r = 0; r < 4; r++)
                    sm.fepi[(lr + r) * 132 + wx * 64 + ni * 16 + l15] = acc[mi][ni][r];
        }
        __syncthreads();
#pragma unroll
        for (int i = 0; i < 8; i++) {
            int flat = i * 1024 + tid * 4;
            int lrow = flat >> 7, col = flat & 127;
            float4 vv = *(const float4*)&sm.fepi[lrow * 132 + col];
            int m = (lrow & 31) + (lrow >> 5) * 64 + ph * 32;
            *(float4*)&out[(size_t)(m0 + m) * 512 + n0 + col] = vv;
        }
        __syncthreads();
    }
}

extern "C" void kernel_launch(void* const* d_in, const int* in_sizes, int n_in,
                              void* d_out, int out_size, void* d_ws, size_t ws_size,
                              hipStream_t stream) {
    const float* x     = (const float*)d_in[0];   // [2,4096,512]
    const float* w_qkv = (const float*)d_in[1];   // [1536,512]
    const float* w_o   = (const float*)d_in[2];   // [512,512]
    float* out = (float*)d_out;

    const size_t N_X   = (size_t)Bq * Lq * Dq;        // 4194304
    const size_t N_WQ  = (size_t)3 * Dq * Dq;         // 786432
    const size_t N_WO  = (size_t)Dq * Dq;             // 262144
    const size_t N_QKV = (size_t)Bq * Hq * Lq * DKq;  // 4194304 each

    u16* xb  = (u16*)d_ws;       // castall in; dead after qkv -> op0
    u16* wqb = xb + N_X;         // dead after qkv -> denp
    u16* wob = wqb + N_WQ;
    u16* qb  = wob + N_WO;
    u16* kb  = qb + N_QKV;
    u16* vt  = kb + N_QKV;
    u16* o1r = vt + N_QKV;       // op1 region (~42 MB total, as R4)

    _Float16* op0  = (_Float16*)xb;
    _Float16* op1  = (_Float16*)o1r;
    float*    denp = (float*)wqb;

    castall<<<dim3(5120), 256, 0, stream>>>(x, w_qkv, w_o, xb, wqb, wob);
    qkv_gemm<<<dim3(64, 12), 256, 0, stream>>>(xb, wqb, qb, kb, vt);
    attn_kern<<<dim3(1024), 256, 0, stream>>>(qb, kb, vt, op0, op1, denp);
    out_gemm<<<dim3(64, 4), 256, 0, stream>>>(op0, op1, denp, wob, out);
}

// Round 8
// 197.082 us; speedup vs baseline: 1.7745x; 1.7745x over previous
//
#include <hip/hip_runtime.h>

// B=2, L=4096, D=512, H=8, DK=64. out = Attn(x W_qkv^T) W_o^T, fp32 io.
// R8: consolidation. attn = exact R4 structure (96.6us proven; 3 blocks/CU
// with L2-resident K/V -- R7 showed 4 blocks/CU thrashes HBM). qkv/out = R5's
// LDS-bounced epilogues (best measured rest). New: fold log2e into q prescale
// -> raw v_exp_f32 (exp2), removing 16 v_mul/wave-iter from the VALU pipe.

#define Bq 2
#define Lq 4096
#define Dq 512
#define Hq 8
#define DKq 64
#define PST 72  // P row stride (elems): 144B -> 2-way bank aliasing only (free)

using short8  = __attribute__((ext_vector_type(8))) short;
using ushort8 = __attribute__((ext_vector_type(8))) unsigned short;
using float4v = __attribute__((ext_vector_type(4))) float;
using half4   = __attribute__((ext_vector_type(4))) _Float16;
typedef unsigned short u16;
typedef unsigned int   u32;

__device__ __forceinline__ u16 f2bf(float f) {
    u32 u = __float_as_uint(f);
    u += 0x7fffu + ((u >> 16) & 1u);   // RNE
    return (u16)(u >> 16);
}

__device__ __forceinline__ float exp2fast(float x) {
#if __has_builtin(__builtin_amdgcn_exp2f)
    return __builtin_amdgcn_exp2f(x);
#else
    return exp2f(x);
#endif
}

__device__ __forceinline__ float4v mfma16(short8 a, short8 b, float4v c) {
    return __builtin_amdgcn_mfma_f32_16x16x32_bf16(a, b, c, 0, 0, 0);
}

__device__ __forceinline__ void gload_lds16(const u16* g, u16* l) {
    __builtin_amdgcn_global_load_lds(
        (const __attribute__((address_space(1))) unsigned int*)g,
        (__attribute__((address_space(3))) unsigned int*)l,
        16, 0, 0);
}

// ---------------- fused cast fp32 -> bf16 ----------------
__global__ __launch_bounds__(256) void castall(const float* __restrict__ x,
                                               const float* __restrict__ wq,
                                               const float* __restrict__ wo,
                                               u16* __restrict__ xb,
                                               u16* __restrict__ wqb,
                                               u16* __restrict__ wob) {
    int g = blockIdx.x;
    const float* s; u16* d; int base;
    if (g < 4096)      { s = x;  d = xb;  base = g * 1024; }
    else if (g < 4864) { s = wq; d = wqb; base = (g - 4096) * 1024; }
    else               { s = wo; d = wob; base = (g - 4864) * 1024; }
    int i = base + threadIdx.x * 4;
    float4 f = *(const float4*)&s[i];
    ushort4 o;
    o.x = f2bf(f.x); o.y = f2bf(f.y); o.z = f2bf(f.z); o.w = f2bf(f.w);
    *(ushort4*)&d[i] = o;
}

// ---------------- QKV proj: 128x128 tile; LDS-bounced coalesced epilogue -----
// q prescaled by 0.125*log2(e) (softmax done in exp2 domain); k,v plain.
__global__ __launch_bounds__(256) void qkv_gemm(const u16* __restrict__ A,
                                                const u16* __restrict__ Bw,
                                                u16* __restrict__ qb,
                                                u16* __restrict__ kb,
                                                u16* __restrict__ vt) {
    __shared__ __align__(16) union {
        struct { u16 A[128 * 64]; u16 B[128 * 64]; } s;
        u16 epi[128 * 134];
    } sm;
    const int m0 = blockIdx.x * 128, n0 = blockIdx.y * 128;
    const int tid = threadIdx.x, w = tid >> 6, lane = tid & 63;
    const int l15 = lane & 15, quad = lane >> 4;
    const int wy = w & 1, wx = w >> 1;
    const int r8 = lane >> 3, c8 = lane & 7, csw = c8 ^ r8;
    const int sw = l15 & 7;

    float4v acc[4][4];
    float4v zero = {0.f, 0.f, 0.f, 0.f};
#pragma unroll
    for (int mi = 0; mi < 4; mi++)
#pragma unroll
        for (int ni = 0; ni < 4; ni++) acc[mi][ni] = zero;

    for (int k0 = 0; k0 < 512; k0 += 64) {
#pragma unroll
        for (int i = 0; i < 4; i++) {
            int row = w * 32 + i * 8;
            gload_lds16(&A[(size_t)(m0 + row + r8) * 512 + k0 + csw * 8], &sm.s.A[row * 64]);
            gload_lds16(&Bw[(size_t)(n0 + row + r8) * 512 + k0 + csw * 8], &sm.s.B[row * 64]);
        }
        __syncthreads();
        short8 af0[4], af1[4], bf0[4], bf1[4];
#pragma unroll
        for (int t = 0; t < 4; t++) {
            int rowA = wy * 64 + t * 16 + l15;
            af0[t] = *(const short8*)&sm.s.A[rowA * 64 + ((quad ^ sw) * 8)];
            af1[t] = *(const short8*)&sm.s.A[rowA * 64 + (((quad + 4) ^ sw) * 8)];
            int rowB = wx * 64 + t * 16 + l15;
            bf0[t] = *(const short8*)&sm.s.B[rowB * 64 + ((quad ^ sw) * 8)];
            bf1[t] = *(const short8*)&sm.s.B[rowB * 64 + (((quad + 4) ^ sw) * 8)];
        }
#pragma unroll
        for (int mi = 0; mi < 4; mi++)
#pragma unroll
            for (int ni = 0; ni < 4; ni++) {
                acc[mi][ni] = mfma16(af0[mi], bf0[ni], acc[mi][ni]);
                acc[mi][ni] = mfma16(af1[mi], bf1[ni], acc[mi][ni]);
            }
        __syncthreads();
    }

    const int sel = n0 >> 9;   // block-uniform: 0=q,1=k,2=v
    if (sel < 2) {
        const float sc = (sel == 0) ? 0.18033688f : 1.0f;  // 0.125*log2(e)
#pragma unroll
        for (int mi = 0; mi < 4; mi++)
#pragma unroll
            for (int ni = 0; ni < 4; ni++)
#pragma unroll
                for (int r = 0; r < 4; r++)
                    sm.epi[(wy * 64 + mi * 16 + quad * 4 + r) * 134 + wx * 64 + ni * 16 + l15] =
                        f2bf(acc[mi][ni][r] * sc);
        __syncthreads();
        u16* tgt = (sel == 0) ? qb : kb;
#pragma unroll
        for (int i = 0; i < 8; i++) {
            int flat = i * 2048 + tid * 8;
            int row = flat >> 7, col = flat & 127;
            ushort8 vv = *(const ushort8*)&sm.epi[row * 134 + col];
            int dg = (n0 & 511) + col, h = dg >> 6, dk = dg & 63;
            int mm = m0 + row, b = mm >> 12, l = mm & 4095;
            *(ushort8*)&tgt[((size_t)(b * Hq + h) * Lq + l) * DKq + dk] = vv;
        }
    } else {
#pragma unroll
        for (int mi = 0; mi < 4; mi++)
#pragma unroll
            for (int ni = 0; ni < 4; ni++) {
                ushort4 v4;
                v4.x = f2bf(acc[mi][ni][0]); v4.y = f2bf(acc[mi][ni][1]);
                v4.z = f2bf(acc[mi][ni][2]); v4.w = f2bf(acc[mi][ni][3]);
                *(ushort4*)&sm.epi[(wx * 64 + ni * 16 + l15) * 134 + wy * 64 + mi * 16 + quad * 4] = v4;
            }
        __syncthreads();
#pragma unroll
        for (int i = 0; i < 8; i++) {
            int flat = i * 2048 + tid * 8;
            int vrow = flat >> 7, vcol = flat & 127;
            ushort8 vv = *(const ushort8*)&sm.epi[vrow * 134 + vcol];
            int dg = (n0 & 511) + vrow, h = dg >> 6, dk = dg & 63;
            int mm = m0 + vcol, b = mm >> 12, l = mm & 4095;
            *(ushort8*)&vt[((size_t)(b * Hq + h) * DKq + dk) * Lq + l] = vv;
        }
    }
}

// ---------------- attention: exact R4 structure (96.6us proven) -------------
__global__ __launch_bounds__(256, 4) void attn_kern(const u16* __restrict__ qb,
                                                    const u16* __restrict__ kb,
                                                    const u16* __restrict__ vt,
                                                    _Float16* __restrict__ op0,
                                                    _Float16* __restrict__ op1,
                                                    float* __restrict__ denp) {
    __shared__ __align__(16) u16 Ks[64 * 64];
    __shared__ __align__(16) u16 Vs[64 * 64];
    __shared__ __align__(16) u16 Ps[4 * 32 * PST];
    const int g = blockIdx.x;          // 1024
    const int xcd = g & 7, idx = g >> 3;
    const int bh = xcd * 2 + (idx & 1);
    const int rest = idx >> 1;
    const int split = rest & 1;
    const int q0 = (rest >> 1) * 128;
    const int tid = threadIdx.x;
    const int w = tid >> 6, lane = tid & 63, l15 = lane & 15, quad = lane >> 4;
    const int r8 = lane >> 3, c8 = lane & 7, csw = c8 ^ r8;
    const int sw = l15 & 7;

    const u16* qbase = qb + (size_t)bh * Lq * DKq;
    const u16* kbase = kb + (size_t)bh * Lq * DKq;
    const u16* vbase = vt + (size_t)bh * DKq * Lq;

    short8 aq0[2], aq1[2];
#pragma unroll
    for (int s = 0; s < 2; s++) {
        int qrow = q0 + w * 32 + s * 16 + l15;
        aq0[s] = *(const short8*)&qbase[(size_t)qrow * DKq + quad * 8];
        aq1[s] = *(const short8*)&qbase[(size_t)qrow * DKq + 32 + quad * 8];
    }

    short8 ones8;
#pragma unroll
    for (int j = 0; j < 8; j++) ones8[j] = (short)0x3F80;  // bf16 1.0

    float4v zero = {0.f, 0.f, 0.f, 0.f};
    float4v oacc[2][4], den[2];
#pragma unroll
    for (int s = 0; s < 2; s++) {
        den[s] = zero;
#pragma unroll
        for (int n = 0; n < 4; n++) oacc[s][n] = zero;
    }

    u16* Pw = Ps + w * 32 * PST;
    const int j0base = split * 2048;

    for (int jt = 0; jt < 32; jt++) {
        int j0 = j0base + jt * 64;
        if (w < 2) {
#pragma unroll
            for (int i = 0; i < 4; i++) {
                int base = w * 32 + i * 8;
                gload_lds16(&kbase[(size_t)(j0 + base + r8) * DKq + csw * 8], &Ks[base * 64]);
            }
        } else {
#pragma unroll
            for (int i = 0; i < 4; i++) {
                int base = (w - 2) * 32 + i * 8;
                gload_lds16(&vbase[(size_t)(base + r8) * Lq + j0 + csw * 8], &Vs[base * 64]);
            }
        }
        __syncthreads();

        short8 kf0[4], kf1[4], vf0[4], vf1[4];
#pragma unroll
        for (int n = 0; n < 4; n++) {
            int row = n * 16 + l15;
            kf0[n] = *(const short8*)&Ks[row * 64 + ((quad ^ sw) * 8)];
            kf1[n] = *(const short8*)&Ks[row * 64 + (((quad + 4) ^ sw) * 8)];
            vf0[n] = *(const short8*)&Vs[row * 64 + ((quad ^ sw) * 8)];
            vf1[n] = *(const short8*)&Vs[row * 64 + (((quad + 4) ^ sw) * 8)];
        }

        // S^T = K Q^T -> P = exp2(S) -> LDS (b64 packed writes)
#pragma unroll
        for (int s = 0; s < 2; s++) {
#pragma unroll
            for (int nk = 0; nk < 4; nk++) {
                float4v sv = zero;
                sv = mfma16(kf0[nk], aq0[s], sv);
                sv = mfma16(kf1[nk], aq1[s], sv);
                u32 u0 = __float_as_uint(exp2fast(sv[0])) + 0x8000u;
                u32 u1 = __float_as_uint(exp2fast(sv[1])) + 0x8000u;
                u32 u2 = __float_as_uint(exp2fast(sv[2])) + 0x8000u;
                u32 u3 = __float_as_uint(exp2fast(sv[3])) + 0x8000u;
                uint2 pv;
                pv.x = __builtin_amdgcn_perm(u1, u0, 0x07060302u);
                pv.y = __builtin_amdgcn_perm(u3, u2, 0x07060302u);
                *(uint2*)&Pw[(s * 16 + l15) * PST + nk * 16 + quad * 4] = pv;
            }
        }

        // O += P V ; den += P . 1
#pragma unroll
        for (int s = 0; s < 2; s++) {
            short8 ap0 = *(const short8*)&Pw[(s * 16 + l15) * PST + quad * 8];
            short8 ap1 = *(const short8*)&Pw[(s * 16 + l15) * PST + 32 + quad * 8];
            den[s] = mfma16(ap0, ones8, den[s]);
            den[s] = mfma16(ap1, ones8, den[s]);
#pragma unroll
            for (int n = 0; n < 4; n++) {
                oacc[s][n] = mfma16(ap0, vf0[n], oacc[s][n]);
                oacc[s][n] = mfma16(ap1, vf1[n], oacc[s][n]);
            }
        }
        __syncthreads();
    }

    // epilogue: write normalized partial O (fp16) + partial den (fp32)
    _Float16* op = split ? op1 : op0;
#pragma unroll
    for (int s = 0; s < 2; s++)
#pragma unroll
        for (int r = 0; r < 4; r++) {
            float dv = den[s][r];
            float rd = __builtin_amdgcn_rcpf(dv);
            int row = q0 + w * 32 + s * 16 + quad * 4 + r;
            if (l15 == 0) denp[(size_t)(split * 16 + bh) * Lq + row] = dv;
#pragma unroll
            for (int n = 0; n < 4; n++)
                op[((size_t)bh * Lq + row) * DKq + n * 16 + l15] =
                    (_Float16)(oacc[s][n][r] * rd);
        }
}

// ---------------- combine: ctx = (o0*d0 + o1*d1)/(d0+d1), bf16 --------------
__global__ __launch_bounds__(256) void combine(const _Float16* __restrict__ op0,
                                               const _Float16* __restrict__ op1,
                                               const float* __restrict__ denp,
                                               u16* __restrict__ ctxq) {
    int t = blockIdx.x * 256 + threadIdx.x;  // 1,048,576
    int dk4 = t & 15, l = (t >> 4) & 4095, bh = t >> 16;
    size_t r0 = (size_t)bh * Lq + l;
    half4 h0 = *(const half4*)&op0[r0 * DKq + dk4 * 4];
    half4 h1 = *(const half4*)&op1[r0 * DKq + dk4 * 4];
    float d0 = denp[r0];
    float d1 = denp[(size_t)(16 + bh) * Lq + l];
    float rs = __builtin_amdgcn_rcpf(d0 + d1);
    int b = bh >> 3, h = bh & 7;
    ushort4 o;
    o.x = f2bf(((float)h0.x * d0 + (float)h1.x * d1) * rs);
    o.y = f2bf(((float)h0.y * d0 + (float)h1.y * d1) * rs);
    o.z = f2bf(((float)h0.z * d0 + (float)h1.z * d1) * rs);
    o.w = f2bf(((float)h0.w * d0 + (float)h1.w * d1) * rs);
    *(ushort4*)&ctxq[((size_t)(b * Lq + l)) * Dq + h * DKq + dk4 * 4] = o;
}

// ---------------- output projection: fp32 out, LDS-bounced epilogue ---------
__global__ __launch_bounds__(256) void out_gemm(const u16* __restrict__ A,
                                                const u16* __restrict__ Bw,
                                                float* __restrict__ out) {
    __shared__ __align__(16) union {
        struct { u16 A[128 * 64]; u16 B[128 * 64]; } s;
        float fepi[64 * 132];
    } sm;
    const int m0 = blockIdx.x * 128, n0 = blockIdx.y * 128;
    const int tid = threadIdx.x, w = tid >> 6, lane = tid & 63;
    const int l15 = lane & 15, quad = lane >> 4;
    const int wy = w & 1, wx = w >> 1;
    const int r8 = lane >> 3, c8 = lane & 7, csw = c8 ^ r8;
    const int sw = l15 & 7;

    float4v acc[4][4];
    float4v zero = {0.f, 0.f, 0.f, 0.f};
#pragma unroll
    for (int mi = 0; mi < 4; mi++)
#pragma unroll
        for (int ni = 0; ni < 4; ni++) acc[mi][ni] = zero;

    for (int k0 = 0; k0 < 512; k0 += 64) {
#pragma unroll
        for (int i = 0; i < 4; i++) {
            int row = w * 32 + i * 8;
            gload_lds16(&A[(size_t)(m0 + row + r8) * 512 + k0 + csw * 8], &sm.s.A[row * 64]);
            gload_lds16(&Bw[(size_t)(n0 + row + r8) * 512 + k0 + csw * 8], &sm.s.B[row * 64]);
        }
        __syncthreads();
        short8 af0[4], af1[4], bf0[4], bf1[4];
#pragma unroll
        for (int t = 0; t < 4; t++) {
            int rowA = wy * 64 + t * 16 + l15;
            af0[t] = *(const short8*)&sm.s.A[rowA * 64 + ((quad ^ sw) * 8)];
            af1[t] = *(const short8*)&sm.s.A[rowA * 64 + (((quad + 4) ^ sw) * 8)];
            int rowB = wx * 64 + t * 16 + l15;
            bf0[t] = *(const short8*)&sm.s.B[rowB * 64 + ((quad ^ sw) * 8)];
            bf1[t] = *(const short8*)&sm.s.B[rowB * 64 + (((quad + 4) ^ sw) * 8)];
        }
#pragma unroll
        for (int mi = 0; mi < 4; mi++)
#pragma unroll
            for (int ni = 0; ni < 4; ni++) {
                acc[mi][ni] = mfma16(af0[mi], bf0[ni], acc[mi][ni]);
                acc[mi][ni] = mfma16(af1[mi], bf1[ni], acc[mi][ni]);
            }
        __syncthreads();
    }

#pragma unroll
    for (int ph = 0; ph < 2; ph++) {
#pragma unroll
        for (int mh = 0; mh < 2; mh++) {
            int mi = ph * 2 + mh;
            int lr = wy * 32 + mh * 16 + quad * 4;
#pragma unroll
            for (int ni = 0; ni < 4; ni++)
#pragma unroll
                for (int r = 0; r < 4; r++)
                    sm.fepi[(lr + r) * 132 + wx * 64 + ni * 16 + l15] = acc[mi][ni][r];
        }
        __syncthreads();
#pragma unroll
        for (int i = 0; i < 8; i++) {
            int flat = i * 1024 + tid * 4;
            int lrow = flat >> 7, col = flat & 127;
            float4 vv = *(const float4*)&sm.fepi[lrow * 132 + col];
            int m = (lrow & 31) + (lrow >> 5) * 64 + ph * 32;
            *(float4*)&out[(size_t)(m0 + m) * 512 + n0 + col] = vv;
        }
        __syncthreads();
    }
}

extern "C" void kernel_launch(void* const* d_in, const int* in_sizes, int n_in,
                              void* d_out, int out_size, void* d_ws, size_t ws_size,
                              hipStream_t stream) {
    const float* x     = (const float*)d_in[0];   // [2,4096,512]
    const float* w_qkv = (const float*)d_in[1];   // [1536,512]
    const float* w_o   = (const float*)d_in[2];   // [512,512]
    float* out = (float*)d_out;

    const size_t N_X   = (size_t)Bq * Lq * Dq;        // 4194304
    const size_t N_WQ  = (size_t)3 * Dq * Dq;         // 786432
    const size_t N_WO  = (size_t)Dq * Dq;             // 262144
    const size_t N_QKV = (size_t)Bq * Hq * Lq * DKq;  // 4194304 each

    u16* xb  = (u16*)d_ws;       // castall in; dead after qkv -> op0
    u16* wqb = xb + N_X;         // dead after qkv -> denp
    u16* wob = wqb + N_WQ;
    u16* qb  = wob + N_WO;       // dead after attn -> final ctx
    u16* kb  = qb + N_QKV;
    u16* vt  = kb + N_QKV;
    u16* o1r = vt + N_QKV;       // op1 region

    _Float16* op0  = (_Float16*)xb;
    _Float16* op1  = (_Float16*)o1r;
    float*    denp = (float*)wqb;
    u16*      ctxq = qb;

    castall<<<dim3(5120), 256, 0, stream>>>(x, w_qkv, w_o, xb, wqb, wob);
    qkv_gemm<<<dim3(64, 12), 256, 0, stream>>>(xb, wqb, qb, kb, vt);
    attn_kern<<<dim3(1024), 256, 0, stream>>>(qb, kb, vt, op0, op1, denp);
    combine<<<dim3(4096), 256, 0, stream>>>(op0, op1, denp, ctxq);
    out_gemm<<<dim3(64, 4), 256, 0, stream>>>(ctxq, wob, out);
}